// Round 7
// baseline (5013.363 us; speedup 1.0000x reference)
//
#include <hip/hip_runtime.h>

typedef _Float16 f16;
typedef _Float16 f16x2 __attribute__((ext_vector_type(2)));
typedef _Float16 f16x8 __attribute__((ext_vector_type(8)));
typedef float f32x4 __attribute__((ext_vector_type(4)));
typedef unsigned int u32;
typedef unsigned short u16;

#define B_SZ 64
#define T_SZ 512
#define DIN 768
#define H_SZ 256
#define TH 768               // 3*H
#define M_ROWS (B_SZ * T_SZ) // 32768

// Workspace layout (bytes). Total = 69,861,376 B (~66.6 MB).
#define O_WT1 ((size_t)0)
#define O_WT2 (O_WT1 + (size_t)768 * 768 * 2)
#define O_H1 (O_WT2 + (size_t)768 * 1024 * 2)
#define O_G (O_H1 + (size_t)M_ROWS * H_SZ * 2)

__device__ __forceinline__ u32 pk2(float a, float b) {
  union { f16 h[2]; u32 u; } x;
  x.h[0] = (f16)a;
  x.h[1] = (f16)b;
  return x.u;
}

__device__ __forceinline__ float sigmf_(float x) {
  return 1.0f / (1.0f + __expf(-x));
}
__device__ __forceinline__ float tanhf_(float x) {
  float e = __expf(-2.0f * fabsf(x));
  float r = (1.0f - e) / (1.0f + e);
  return copysignf(r, x);
}

// ---------------------------------------------------------------------------
// Transpose+convert: W [K][N] fp32 -> Wt [N][K] fp16  (used for W_ih only)
// ---------------------------------------------------------------------------
__global__ __launch_bounds__(256) void k_transpose(const float* __restrict__ W,
                                                   f16* __restrict__ Wt, int K,
                                                   int N) {
  __shared__ f16 tile[32][33];
  int tx = threadIdx.x, ty = threadIdx.y;
  int n0 = blockIdx.x * 32, k0 = blockIdx.y * 32;
#pragma unroll
  for (int q = 0; q < 4; ++q) {
    int k = k0 + ty + q * 8;
    tile[ty + q * 8][tx] = (f16)W[(size_t)k * N + n0 + tx];
  }
  __syncthreads();
#pragma unroll
  for (int q = 0; q < 4; ++q) {
    int n = n0 + ty + q * 8;
    Wt[(size_t)n * K + k0 + tx] = tile[tx][ty + q * 8];
  }
}

// ---------------------------------------------------------------------------
// fp16 MFMA GEMM: C[M][768] = A @ Bt^T + bias.
// ---------------------------------------------------------------------------
#define LDK 40 // padded LDS k-stride (halves)
__global__ __launch_bounds__(256, 2) void k_gemm(
    const float* __restrict__ A32, const f16* __restrict__ AH,
    const f16* __restrict__ Bt, const float* __restrict__ bias,
    f16* __restrict__ C, int K, int bstride) {
  __shared__ __align__(16) f16 Asm[128 * LDK];
  __shared__ __align__(16) f16 Bsm[128 * LDK];
  int tid = threadIdx.x;
  int lane = tid & 63, wave = tid >> 6;
  int wm = wave & 1, wn = wave >> 1;
  int fm = lane & 15, fk = (lane >> 4) * 8;
  int srow = tid >> 1, skp = (tid & 1) * 16;
  size_t r0 = (size_t)blockIdx.y * 128;
  int n0 = blockIdx.x * 128;
  f32x4 acc[4][4] = {};

  for (int k0 = 0; k0 < K; k0 += 32) {
    __syncthreads();
    if (k0 < DIN) {
      const float* src = A32 + (r0 + srow) * DIN + k0 + skp;
      float4 v0 = *(const float4*)(src);
      float4 v1 = *(const float4*)(src + 4);
      float4 v2 = *(const float4*)(src + 8);
      float4 v3 = *(const float4*)(src + 12);
      uint4 w0 = make_uint4(pk2(v0.x, v0.y), pk2(v0.z, v0.w), pk2(v1.x, v1.y),
                            pk2(v1.z, v1.w));
      uint4 w1 = make_uint4(pk2(v2.x, v2.y), pk2(v2.z, v2.w), pk2(v3.x, v3.y),
                            pk2(v3.z, v3.w));
      *(uint4*)&Asm[srow * LDK + skp] = w0;
      *(uint4*)&Asm[srow * LDK + skp + 8] = w1;
    } else {
      const uint4* src =
          (const uint4*)(AH + (r0 + srow) * H_SZ + (k0 - DIN) + skp);
      *(uint4*)&Asm[srow * LDK + skp] = src[0];
      *(uint4*)&Asm[srow * LDK + skp + 8] = src[1];
    }
    const uint4* bsrc =
        (const uint4*)(Bt + (size_t)(n0 + srow) * bstride + k0 + skp);
    *(uint4*)&Bsm[srow * LDK + skp] = bsrc[0];
    *(uint4*)&Bsm[srow * LDK + skp + 8] = bsrc[1];
    __syncthreads();

    f16x8 af[4], bf[4];
#pragma unroll
    for (int mt = 0; mt < 4; ++mt)
      af[mt] = *(const f16x8*)&Asm[(wm * 64 + mt * 16 + fm) * LDK + fk];
#pragma unroll
    for (int nt = 0; nt < 4; ++nt)
      bf[nt] = *(const f16x8*)&Bsm[(wn * 64 + nt * 16 + fm) * LDK + fk];
#pragma unroll
    for (int mt = 0; mt < 4; ++mt)
#pragma unroll
      for (int nt = 0; nt < 4; ++nt)
        acc[mt][nt] = __builtin_amdgcn_mfma_f32_16x16x32_f16(af[mt], bf[nt],
                                                             acc[mt][nt], 0, 0, 0);
  }

  int ccol = lane & 15, crb = (lane >> 4) * 4;
#pragma unroll
  for (int nt = 0; nt < 4; ++nt) {
    int col = n0 + wn * 64 + nt * 16 + ccol;
    float bv = bias[col];
#pragma unroll
    for (int mt = 0; mt < 4; ++mt) {
      size_t rb = r0 + wm * 64 + mt * 16 + crb;
#pragma unroll
      for (int rg = 0; rg < 4; ++rg)
        C[(rb + rg) * TH + col] = (f16)(acc[mt][nt][rg] + bv);
    }
  }
}

// ---------------------------------------------------------------------------
// Recurrence v4 (MFMA-batched): 4 blocks x 512 thr; block owns 16 batches.
// Per step: gh[16 x 768] = h[16 x 256] @ W_hh via mfma_16x16x32_f16.
// Wave w owns h-cols [32w,32w+32) = 6 N-tiles {r,z,n} x {s=0,1}; its 48
// B-fragments (192 regs/thread) are loop-invariant named values -> the
// allocator parks them in AGPRs, and MFMA reads AGPRs DIRECTLY (unlike
// v_dot2, which needed an accvgpr_read per use -- that was the 595us tax).
// r/z/n for one (batch,hcol) land in the SAME lane (C/D layout), so gates
// are in-lane; h carried in lane regs + double-buffered LDS fp16 for the
// next step's A-fragments. One barrier per step.
// ---------------------------------------------------------------------------
#define WST 48   // LDS k-stride (halves) of staged W chunk [768 n][32 k]
#define HST 280  // LDS stride (halves) of h rows [16][HST], 16B-aligned
#define HBUF (16 * HST)

__device__ __forceinline__ void stage_chunk(const float* __restrict__ Whh,
                                            f16* __restrict__ s_wstage, int c,
                                            int tid) {
#pragma unroll
  for (int qq = 0; qq < 12; ++qq) {
    int idx4 = tid + qq * 512; // 6144 float4 = 32 rows x 192 float4
    int kk = idx4 / 192;
    int n4 = (idx4 - kk * 192) * 4;
    const float* sp = Whh + ((size_t)c * 32 + kk) * TH + n4;
    float4 v = *(const float4*)sp;
    s_wstage[(n4 + 0) * WST + kk] = (f16)v.x;
    s_wstage[(n4 + 1) * WST + kk] = (f16)v.y;
    s_wstage[(n4 + 2) * WST + kk] = (f16)v.z;
    s_wstage[(n4 + 3) * WST + kk] = (f16)v.w;
  }
}

#define DECLBF(g, s)                                                           \
  f16x8 bf##g##_##s##_0, bf##g##_##s##_1, bf##g##_##s##_2, bf##g##_##s##_3,    \
      bf##g##_##s##_4, bf##g##_##s##_5, bf##g##_##s##_6, bf##g##_##s##_7

#define LDF1(g, s, q)                                                          \
  bf##g##_##s##_##q =                                                          \
      *(const f16x8*)&s_wstage[(size_t)(256 * (g) + cwb + 16 * (s)) * WST +    \
                               kup8]

#define LDFRAGS(q)                                                             \
  LDF1(0, 0, q);                                                               \
  LDF1(0, 1, q);                                                               \
  LDF1(1, 0, q);                                                               \
  LDF1(1, 1, q);                                                               \
  LDF1(2, 0, q);                                                               \
  LDF1(2, 1, q)

#define STAGE_AND_FRAGS(q)                                                     \
  __syncthreads();                                                             \
  stage_chunk(Whh, s_wstage, q, tid);                                          \
  __syncthreads();                                                             \
  LDFRAGS(q)

#define MFMA16(d, a, b)                                                        \
  d = __builtin_amdgcn_mfma_f32_16x16x32_f16(a, b, d, 0, 0, 0)

#define MM6(AF, q)                                                             \
  MFMA16(accr0, AF, bf0_0_##q);                                                \
  MFMA16(accr1, AF, bf0_1_##q);                                                \
  MFMA16(accz0, AF, bf1_0_##q);                                                \
  MFMA16(accz1, AF, bf1_1_##q);                                                \
  MFMA16(accn0, AF, bf2_0_##q);                                                \
  MFMA16(accn1, AF, bf2_1_##q)

#define AFLD(i, q)                                                             \
  af##i = *(const f16x8*)&s_h[curb + l15 * HST + (q)*32 + kup8]

#define DGI(s, rg) f16 gir##s##rg, giz##s##rg, gin##s##rg
#define LDGI(s, rg)                                                            \
  {                                                                            \
    const f16* gp =                                                            \
        G + ((size_t)gbase_row + (rg)*T_SZ) * TH + cwb + 16 * (s);             \
    gir##s##rg = gp[0];                                                        \
    giz##s##rg = gp[256];                                                      \
    gin##s##rg = gp[512];                                                      \
  }

#define GATE(s, rg, ACCR, ACCZ, ACCN, HOLD)                                    \
  {                                                                            \
    float rr = sigmf_((float)gir##s##rg + ACCR[rg] + bbr##s);                  \
    float zz = sigmf_((float)giz##s##rg + ACCZ[rg] + bbz##s);                  \
    float nn = tanhf_((float)gin##s##rg + rr * (ACCN[rg] + bbn##s));           \
    float ho = HOLD[rg];                                                       \
    float hn = om * ho + invt * ((1.0f - zz) * nn + zz * ho);                  \
    HOLD[rg] = hn;                                                             \
    s_h[nxtb + (mm + rg) * HST + cwb + 16 * (s)] = (f16)hn;                    \
    out_g[((size_t)gbase_row + (rg)*T_SZ) * 512 + out_off + cwb + 16 * (s)] =  \
        hn;                                                                    \
    if (H1out)                                                                 \
      H1out[((size_t)gbase_row + (rg)*T_SZ) * 256 + cwb + 16 * (s)] =          \
          (f16)hn;                                                             \
  }

__global__ __launch_bounds__(512, 1) void k_rec(
    const f16* __restrict__ G, const float* __restrict__ Whh,
    const float* __restrict__ bhh, const float* __restrict__ tau,
    float* __restrict__ out_g, int out_off, f16* __restrict__ H1out) {
  __shared__ __align__(16) f16 s_wstage[768 * WST]; // 72 KB staged W chunk
  __shared__ __align__(16) f16 s_h[2 * HBUF];       // 17.5 KB h double-buffer

  int tid = threadIdx.x;
  int lane = tid & 63;
  int w = tid >> 6;          // wave 0..7: h-cols [32w, 32w+32)
  int l15 = lane & 15;       // col-in-tile / h row (A)
  int kup = lane >> 4;       // k-subgroup 0..3
  int kup8 = kup * 8;
  int mm = kup * 4;          // batch-row base for C/D rows
  int cwb = 32 * w + l15;    // gate col base (g=0,s=0)
  int b0 = blockIdx.x * 16;  // this block's batch range

  // Zero h buffers.
  for (int i = tid; i < 2 * HBUF; i += 512) s_h[i] = (f16)0.f;

  // --- Load W_hh into MFMA B-fragments: 48 named f16x8 (192 regs) ---
  DECLBF(0, 0); DECLBF(0, 1); DECLBF(1, 0);
  DECLBF(1, 1); DECLBF(2, 0); DECLBF(2, 1);
  STAGE_AND_FRAGS(0);
  STAGE_AND_FRAGS(1);
  STAGE_AND_FRAGS(2);
  STAGE_AND_FRAGS(3);
  STAGE_AND_FRAGS(4);
  STAGE_AND_FRAGS(5);
  STAGE_AND_FRAGS(6);
  STAGE_AND_FRAGS(7);

  float bbr0 = bhh[cwb], bbr1 = bhh[cwb + 16];
  float bbz0 = bhh[256 + cwb], bbz1 = bhh[256 + cwb + 16];
  float bbn0 = bhh[512 + cwb], bbn1 = bhh[512 + cwb + 16];
  float invt = 1.0f / tau[0];
  float om = 1.0f - invt;
  f32x4 hold0 = {}, hold1 = {};
  __syncthreads();

  for (int t = 0; t < T_SZ; ++t) {
    int cur = t & 1;
    int curb = cur * HBUF, nxtb = HBUF - curb;
    size_t gbase_row = (size_t)(b0 + mm) * T_SZ + t;

    // gi loads for s=0 (issued early, consumed after MFMA).
    DGI(0, 0); DGI(0, 1); DGI(0, 2); DGI(0, 3);
    LDGI(0, 0); LDGI(0, 1); LDGI(0, 2); LDGI(0, 3);

    f32x4 accr0 = {}, accr1 = {}, accz0 = {}, accz1 = {}, accn0 = {},
          accn1 = {};
    f16x8 af0, af1, af2, af3;
    AFLD(0, 0); AFLD(1, 1); AFLD(2, 2); AFLD(3, 3);
    MM6(af0, 0); MM6(af1, 1); MM6(af2, 2); MM6(af3, 3);

    DGI(1, 0); DGI(1, 1); DGI(1, 2); DGI(1, 3);
    LDGI(1, 0); LDGI(1, 1); LDGI(1, 2); LDGI(1, 3);

    AFLD(0, 4); AFLD(1, 5); AFLD(2, 6); AFLD(3, 7);
    MM6(af0, 4); MM6(af1, 5); MM6(af2, 6); MM6(af3, 7);

    GATE(0, 0, accr0, accz0, accn0, hold0);
    GATE(0, 1, accr0, accz0, accn0, hold0);
    GATE(0, 2, accr0, accz0, accn0, hold0);
    GATE(0, 3, accr0, accz0, accn0, hold0);
    GATE(1, 0, accr1, accz1, accn1, hold1);
    GATE(1, 1, accr1, accz1, accn1, hold1);
    GATE(1, 2, accr1, accz1, accn1, hold1);
    GATE(1, 3, accr1, accz1, accn1, hold1);
    __syncthreads();
  }
}

// ---------------------------------------------------------------------------
extern "C" void kernel_launch(void* const* d_in, const int* in_sizes, int n_in,
                              void* d_out, int out_size, void* d_ws,
                              size_t ws_size, hipStream_t stream) {
  const float* enc = (const float*)d_in[0];
  const float* tau1 = (const float*)d_in[1];
  const float* tau2 = (const float*)d_in[2];
  const float* Wih1 = (const float*)d_in[3];
  const float* Whh1 = (const float*)d_in[4];
  const float* bih1 = (const float*)d_in[5];
  const float* bhh1 = (const float*)d_in[6];
  const float* Wih2 = (const float*)d_in[7];
  const float* Whh2 = (const float*)d_in[8];
  const float* bih2 = (const float*)d_in[9];
  const float* bhh2 = (const float*)d_in[10];
  float* out = (float*)d_out;
  char* ws = (char*)d_ws;

  f16* Wt1 = (f16*)(ws + O_WT1); // [768 n][768 k]
  f16* Wt2 = (f16*)(ws + O_WT2); // [768 n][1024 k]
  f16* H1 = (f16*)(ws + O_H1);   // [32768][256] h1 seq, fp16
  f16* G = (f16*)(ws + O_G);     // [32768][768] gi buffer (reused layer1/2)

  // Weight transposes for W_ih (fp32 [k][n] -> fp16 [n][k]).
  k_transpose<<<dim3(24, 24), dim3(32, 8), 0, stream>>>(Wih1, Wt1, 768, 768);
  k_transpose<<<dim3(24, 32), dim3(32, 8), 0, stream>>>(Wih2, Wt2, 1024, 768);

  // Layer 1: gi1 = X @ W_ih1 + b_ih1, then MFMA-batched recurrence.
  k_gemm<<<dim3(6, 256), 256, 0, stream>>>(enc, (const f16*)0, Wt1, bih1, G,
                                           768, 768);
  k_rec<<<4, 512, 0, stream>>>(G, Whh1, bhh1, tau1, out, 0, H1);

  // Layer 2: gi2 = [X | H1] @ W_ih2 + b_ih2, then recurrence.
  k_gemm<<<dim3(6, 256), 256, 0, stream>>>(enc, H1, Wt2, bih2, G, 1024, 1024);
  k_rec<<<4, 512, 0, stream>>>(G, Whh2, bhh2, tau2, out, 256, (f16*)0);
}

// Round 8
// 1538.983 us; speedup vs baseline: 3.2576x; 3.2576x over previous
//
#include <hip/hip_runtime.h>

typedef _Float16 f16;
typedef _Float16 f16x2 __attribute__((ext_vector_type(2)));
typedef _Float16 f16x8 __attribute__((ext_vector_type(8)));
typedef float f32x4 __attribute__((ext_vector_type(4)));
typedef unsigned int u32;
typedef unsigned short u16;

#define B_SZ 64
#define T_SZ 512
#define DIN 768
#define H_SZ 256
#define TH 768               // 3*H
#define M_ROWS (B_SZ * T_SZ) // 32768

// Workspace layout (bytes). Total = 69,861,376 B (~66.6 MB).
#define O_WT1 ((size_t)0)
#define O_WT2 (O_WT1 + (size_t)768 * 768 * 2)
#define O_H1 (O_WT2 + (size_t)768 * 1024 * 2)
#define O_G (O_H1 + (size_t)M_ROWS * H_SZ * 2)

__device__ __forceinline__ u32 pk2(float a, float b) {
  union { f16 h[2]; u32 u; } x;
  x.h[0] = (f16)a;
  x.h[1] = (f16)b;
  return x.u;
}

__device__ __forceinline__ float dot2f(u32 w, u32 h, float acc) {
#if __has_builtin(__builtin_amdgcn_fdot2)
  union { u32 u; f16x2 v; } a, b;
  a.u = w;
  b.u = h;
  return __builtin_amdgcn_fdot2(a.v, b.v, acc, false);
#else
  union { u32 u; f16 h[2]; } a, b;
  a.u = w;
  b.u = h;
  acc = fmaf((float)a.h[0], (float)b.h[0], acc);
  acc = fmaf((float)a.h[1], (float)b.h[1], acc);
  return acc;
#endif
}

__device__ __forceinline__ float sigmf_(float x) {
  return 1.0f / (1.0f + __expf(-x));
}
__device__ __forceinline__ float tanhf_(float x) {
  float e = __expf(-2.0f * fabsf(x));
  float r = (1.0f - e) / (1.0f + e);
  return copysignf(r, x);
}

// ---------------------------------------------------------------------------
// Transpose+convert: W [K][N] fp32 -> Wt [N][K] fp16  (W_ih for the GEMMs)
// ---------------------------------------------------------------------------
__global__ __launch_bounds__(256) void k_transpose(const float* __restrict__ W,
                                                   f16* __restrict__ Wt, int K,
                                                   int N) {
  __shared__ f16 tile[32][33];
  int tx = threadIdx.x, ty = threadIdx.y;
  int n0 = blockIdx.x * 32, k0 = blockIdx.y * 32;
#pragma unroll
  for (int q = 0; q < 4; ++q) {
    int k = k0 + ty + q * 8;
    tile[ty + q * 8][tx] = (f16)W[(size_t)k * N + n0 + tx];
  }
  __syncthreads();
#pragma unroll
  for (int q = 0; q < 4; ++q) {
    int n = n0 + ty + q * 8;
    Wt[(size_t)n * K + k0 + tx] = tile[tx][ty + q * 8];
  }
}

// ---------------------------------------------------------------------------
// fp16 MFMA GEMM: C[M][768] = A @ Bt^T + bias.  (unchanged, proven)
// ---------------------------------------------------------------------------
#define LDK 40 // padded LDS k-stride (halves)
__global__ __launch_bounds__(256, 2) void k_gemm(
    const float* __restrict__ A32, const f16* __restrict__ AH,
    const f16* __restrict__ Bt, const float* __restrict__ bias,
    f16* __restrict__ C, int K, int bstride) {
  __shared__ __align__(16) f16 Asm[128 * LDK];
  __shared__ __align__(16) f16 Bsm[128 * LDK];
  int tid = threadIdx.x;
  int lane = tid & 63, wave = tid >> 6;
  int wm = wave & 1, wn = wave >> 1;
  int fm = lane & 15, fk = (lane >> 4) * 8;
  int srow = tid >> 1, skp = (tid & 1) * 16;
  size_t r0 = (size_t)blockIdx.y * 128;
  int n0 = blockIdx.x * 128;
  f32x4 acc[4][4] = {};

  for (int k0 = 0; k0 < K; k0 += 32) {
    __syncthreads();
    if (k0 < DIN) {
      const float* src = A32 + (r0 + srow) * DIN + k0 + skp;
      float4 v0 = *(const float4*)(src);
      float4 v1 = *(const float4*)(src + 4);
      float4 v2 = *(const float4*)(src + 8);
      float4 v3 = *(const float4*)(src + 12);
      uint4 w0 = make_uint4(pk2(v0.x, v0.y), pk2(v0.z, v0.w), pk2(v1.x, v1.y),
                            pk2(v1.z, v1.w));
      uint4 w1 = make_uint4(pk2(v2.x, v2.y), pk2(v2.z, v2.w), pk2(v3.x, v3.y),
                            pk2(v3.z, v3.w));
      *(uint4*)&Asm[srow * LDK + skp] = w0;
      *(uint4*)&Asm[srow * LDK + skp + 8] = w1;
    } else {
      const uint4* src =
          (const uint4*)(AH + (r0 + srow) * H_SZ + (k0 - DIN) + skp);
      *(uint4*)&Asm[srow * LDK + skp] = src[0];
      *(uint4*)&Asm[srow * LDK + skp + 8] = src[1];
    }
    const uint4* bsrc =
        (const uint4*)(Bt + (size_t)(n0 + srow) * bstride + k0 + skp);
    *(uint4*)&Bsm[srow * LDK + skp] = bsrc[0];
    *(uint4*)&Bsm[srow * LDK + skp + 8] = bsrc[1];
    __syncthreads();

    f16x8 af[4], bf[4];
#pragma unroll
    for (int mt = 0; mt < 4; ++mt)
      af[mt] = *(const f16x8*)&Asm[(wm * 64 + mt * 16 + fm) * LDK + fk];
#pragma unroll
    for (int nt = 0; nt < 4; ++nt)
      bf[nt] = *(const f16x8*)&Bsm[(wn * 64 + nt * 16 + fm) * LDK + fk];
#pragma unroll
    for (int mt = 0; mt < 4; ++mt)
#pragma unroll
      for (int nt = 0; nt < 4; ++nt)
        acc[mt][nt] = __builtin_amdgcn_mfma_f32_16x16x32_f16(af[mt], bf[nt],
                                                             acc[mt][nt], 0, 0, 0);
  }

  int ccol = lane & 15, crb = (lane >> 4) * 4;
#pragma unroll
  for (int nt = 0; nt < 4; ++nt) {
    int col = n0 + wn * 64 + nt * 16 + ccol;
    float bv = bias[col];
#pragma unroll
    for (int mt = 0; mt < 4; ++mt) {
      size_t rb = r0 + wm * 64 + mt * 16 + crb;
#pragma unroll
      for (int rg = 0; rg < 4; ++rg)
        C[(rb + rg) * TH + col] = (f16)(acc[mt][nt][rg] + bv);
    }
  }
}

// ---------------------------------------------------------------------------
// k_prepw: pack W_hh fp32 [256 k][768 col] -> Wp u32 [cc 0..7][c 0..2][tid
// 0..511][8], where thread (cg=tid&255, kh=tid>>8) of k_rec reads, for
// column cg+c*256, the 8 packed fp16 k-pairs of chunk cc (k = kh*128 +
// cc*16 + 2i). One-time, 384 KB output.
// ---------------------------------------------------------------------------
__global__ __launch_bounds__(512) void k_prepw(const float* __restrict__ Whh,
                                               u32* __restrict__ Wp) {
  int gid = blockIdx.x * 512 + threadIdx.x; // 0..12287 = (cc*3+c)*512+t2
  int cc = gid / 1536;
  int r = gid - cc * 1536;
  int c = r >> 9;
  int t2 = r & 511;
  int kh = t2 >> 8, cg = t2 & 255;
  int col = cg + c * 256;
  int kbase = kh * 128 + cc * 16;
  u32 o0 = pk2(Whh[(size_t)(kbase + 0) * TH + col],
               Whh[(size_t)(kbase + 1) * TH + col]);
  u32 o1 = pk2(Whh[(size_t)(kbase + 2) * TH + col],
               Whh[(size_t)(kbase + 3) * TH + col]);
  u32 o2 = pk2(Whh[(size_t)(kbase + 4) * TH + col],
               Whh[(size_t)(kbase + 5) * TH + col]);
  u32 o3 = pk2(Whh[(size_t)(kbase + 6) * TH + col],
               Whh[(size_t)(kbase + 7) * TH + col]);
  u32 o4 = pk2(Whh[(size_t)(kbase + 8) * TH + col],
               Whh[(size_t)(kbase + 9) * TH + col]);
  u32 o5 = pk2(Whh[(size_t)(kbase + 10) * TH + col],
               Whh[(size_t)(kbase + 11) * TH + col]);
  u32 o6 = pk2(Whh[(size_t)(kbase + 12) * TH + col],
               Whh[(size_t)(kbase + 13) * TH + col]);
  u32 o7 = pk2(Whh[(size_t)(kbase + 14) * TH + col],
               Whh[(size_t)(kbase + 15) * TH + col]);
  *(uint4*)&Wp[(size_t)gid * 8] = make_uint4(o0, o1, o2, o3);
  *(uint4*)&Wp[(size_t)gid * 8 + 4] = make_uint4(o4, o5, o6, o7);
}

// ---------------------------------------------------------------------------
// Recurrence v5 (streaming weights): one workgroup (512 thr) per batch row,
// same thread mapping / reduction / gate math as the proven 595us kernel.
// Difference: weights are NOT held per-thread (7 rounds showed the compiler
// never keeps a >=128-reg set resident; every variant re-read scratch each
// step as 192 SCALAR loads). Instead they stream from the L2-resident packed
// buffer Wp as 48 coalesced dwordx4 loads/thread/step, software-pipelined
// through 4 register slots (3-deep prefetch, rolling across the step
// boundary -- Wp addresses are t-invariant). Live register set ~170, all
// statically indexed. waves_per_eu(2,2): allocate for 2 waves/EU (256-reg
// budget) -- grid is 64 blocks on 256 CUs, extra occupancy is worthless.
// ---------------------------------------------------------------------------
#define WSLOT(s)                                                               \
  uint4 sl##s##c0a, sl##s##c0b, sl##s##c1a, sl##s##c1b, sl##s##c2a, sl##s##c2b

#define ISSUE(s, ch)                                                           \
  sl##s##c0a = wp4[((ch)*3 + 0) * 1024 + tid2 + 0];                            \
  sl##s##c0b = wp4[((ch)*3 + 0) * 1024 + tid2 + 1];                            \
  sl##s##c1a = wp4[((ch)*3 + 1) * 1024 + tid2 + 0];                            \
  sl##s##c1b = wp4[((ch)*3 + 1) * 1024 + tid2 + 1];                            \
  sl##s##c2a = wp4[((ch)*3 + 2) * 1024 + tid2 + 0];                            \
  sl##s##c2b = wp4[((ch)*3 + 2) * 1024 + tid2 + 1]

#define DOTS(s, ch)                                                            \
  {                                                                            \
    uint4 hA = hv4[2 * (ch)], hB = hv4[2 * (ch) + 1];                          \
    a0 = dot2f(sl##s##c0a.x, hA.x, a0);                                        \
    a1 = dot2f(sl##s##c1a.x, hA.x, a1);                                        \
    a2 = dot2f(sl##s##c2a.x, hA.x, a2);                                        \
    a0 = dot2f(sl##s##c0a.y, hA.y, a0);                                        \
    a1 = dot2f(sl##s##c1a.y, hA.y, a1);                                        \
    a2 = dot2f(sl##s##c2a.y, hA.y, a2);                                        \
    a0 = dot2f(sl##s##c0a.z, hA.z, a0);                                        \
    a1 = dot2f(sl##s##c1a.z, hA.z, a1);                                        \
    a2 = dot2f(sl##s##c2a.z, hA.z, a2);                                        \
    a0 = dot2f(sl##s##c0a.w, hA.w, a0);                                        \
    a1 = dot2f(sl##s##c1a.w, hA.w, a1);                                        \
    a2 = dot2f(sl##s##c2a.w, hA.w, a2);                                        \
    a0 = dot2f(sl##s##c0b.x, hB.x, a0);                                        \
    a1 = dot2f(sl##s##c1b.x, hB.x, a1);                                        \
    a2 = dot2f(sl##s##c2b.x, hB.x, a2);                                        \
    a0 = dot2f(sl##s##c0b.y, hB.y, a0);                                        \
    a1 = dot2f(sl##s##c1b.y, hB.y, a1);                                        \
    a2 = dot2f(sl##s##c2b.y, hB.y, a2);                                        \
    a0 = dot2f(sl##s##c0b.z, hB.z, a0);                                        \
    a1 = dot2f(sl##s##c1b.z, hB.z, a1);                                        \
    a2 = dot2f(sl##s##c2b.z, hB.z, a2);                                        \
    a0 = dot2f(sl##s##c0b.w, hB.w, a0);                                        \
    a1 = dot2f(sl##s##c1b.w, hB.w, a1);                                        \
    a2 = dot2f(sl##s##c2b.w, hB.w, a2);                                        \
  }

__global__ __launch_bounds__(512)
__attribute__((amdgpu_waves_per_eu(2, 2))) void k_rec(
    const f16* __restrict__ G, const u32* __restrict__ Wp,
    const float* __restrict__ bhh, const float* __restrict__ tau,
    float* __restrict__ out, int out_off, f16* __restrict__ H1out) {
  __shared__ __align__(16) u16 s_h16[256];
  __shared__ float s_h32[256];
  __shared__ float s_part[256 * 3];

  int tid = threadIdx.x;
  int b = blockIdx.x;
  int cg = tid & 255;
  int kh = tid >> 8; // 0 or 1 (wave-uniform)
  int tid2 = tid * 2;

  const uint4* wp4 = (const uint4*)Wp;

  float bb0 = bhh[cg], bb1 = bhh[cg + 256], bb2 = bhh[cg + 512];
  float invt = 1.0f / tau[0];
  float om = 1.0f - invt;
  if (tid < 256) {
    s_h16[tid] = 0;
    s_h32[tid] = 0.0f;
  }
  __syncthreads();

  const f16* gbase = G + (size_t)b * T_SZ * TH;
  float* obase = out + (size_t)b * T_SZ * 512 + out_off;
  f16* hbase = H1out ? H1out + (size_t)b * T_SZ * H_SZ : (f16*)0;
  const uint4* hv4 = (const uint4*)s_h16 + kh * 16;

  // Pipeline slots (24 uint4 = 96 u32, statically indexed).
  WSLOT(0);
  WSLOT(1);
  WSLOT(2);
  WSLOT(3);
  // Prologue: chunks 0..2 in flight.
  ISSUE(0, 0);
  ISSUE(1, 1);
  ISSUE(2, 2);

  for (int t = 0; t < T_SZ; ++t) {
    // gi for this step (independent of h; overlaps the dot phase).
    f16 gg0 = (f16)0.f, gg1 = (f16)0.f, gg2 = (f16)0.f;
    if (tid < 256) {
      const f16* gp = gbase + (size_t)t * TH + cg;
      gg0 = gp[0];
      gg1 = gp[256];
      gg2 = gp[512];
    }
    float a0 = 0.f, a1 = 0.f, a2 = 0.f;
    // 8 chunks, 3-deep rolling prefetch; chunks 8..10 == next step's 0..2
    // (Wp addresses are t-invariant, so reissuing is trivially correct).
    ISSUE(3, 3);
    DOTS(0, 0);
    ISSUE(0, 4);
    DOTS(1, 1);
    ISSUE(1, 5);
    DOTS(2, 2);
    ISSUE(2, 6);
    DOTS(3, 3);
    ISSUE(3, 7);
    DOTS(0, 4);
    ISSUE(0, 0);
    DOTS(1, 5);
    ISSUE(1, 1);
    DOTS(2, 6);
    ISSUE(2, 2);
    DOTS(3, 7);

    if (kh) {
      s_part[cg * 3 + 0] = a0;
      s_part[cg * 3 + 1] = a1;
      s_part[cg * 3 + 2] = a2;
    }
    __syncthreads();
    if (tid < 256) {
      float ghr = a0 + s_part[cg * 3 + 0] + bb0;
      float ghz = a1 + s_part[cg * 3 + 1] + bb1;
      float ghn = a2 + s_part[cg * 3 + 2] + bb2;
      float r = sigmf_((float)gg0 + ghr);
      float z = sigmf_((float)gg1 + ghz);
      float n = tanhf_((float)gg2 + r * ghn);
      float hold = s_h32[cg];
      float hc = (1.0f - z) * n + z * hold;
      float hn2 = om * hold + invt * hc;
      s_h32[cg] = hn2;
      union { f16 h; u16 s; } hb;
      hb.h = (f16)hn2;
      s_h16[cg] = hb.s;
      obase[(size_t)t * 512 + cg] = hn2;
      if (hbase) hbase[(size_t)t * H_SZ + cg] = (f16)hn2;
    }
    __syncthreads();
  }
}

// ---------------------------------------------------------------------------
extern "C" void kernel_launch(void* const* d_in, const int* in_sizes, int n_in,
                              void* d_out, int out_size, void* d_ws,
                              size_t ws_size, hipStream_t stream) {
  const float* enc = (const float*)d_in[0];
  const float* tau1 = (const float*)d_in[1];
  const float* tau2 = (const float*)d_in[2];
  const float* Wih1 = (const float*)d_in[3];
  const float* Whh1 = (const float*)d_in[4];
  const float* bih1 = (const float*)d_in[5];
  const float* bhh1 = (const float*)d_in[6];
  const float* Wih2 = (const float*)d_in[7];
  const float* Whh2 = (const float*)d_in[8];
  const float* bih2 = (const float*)d_in[9];
  const float* bhh2 = (const float*)d_in[10];
  float* out = (float*)d_out;
  char* ws = (char*)d_ws;

  f16* Wt1 = (f16*)(ws + O_WT1); // [768 n][768 k]; Wp1 reuses this after gemm1
  f16* Wt2 = (f16*)(ws + O_WT2); // [768 n][1024 k]; Wp2 reuses after gemm2
  f16* H1 = (f16*)(ws + O_H1);   // [32768][256] h1 seq, fp16
  f16* G = (f16*)(ws + O_G);     // [32768][768] gi buffer (reused layer1/2)
  u32* Wp1 = (u32*)(ws + O_WT1); // 384 KB packed W_hh1 (after gemm1)
  u32* Wp2 = (u32*)(ws + O_WT2); // 384 KB packed W_hh2 (after gemm2)

  // Weight transposes for W_ih (fp32 [k][n] -> fp16 [n][k]).
  k_transpose<<<dim3(24, 24), dim3(32, 8), 0, stream>>>(Wih1, Wt1, 768, 768);
  k_transpose<<<dim3(24, 32), dim3(32, 8), 0, stream>>>(Wih2, Wt2, 1024, 768);

  // Layer 1: gi1 = X @ W_ih1 + b_ih1; pack W_hh1; recurrence.
  k_gemm<<<dim3(6, 256), 256, 0, stream>>>(enc, (const f16*)0, Wt1, bih1, G,
                                           768, 768);
  k_prepw<<<24, 512, 0, stream>>>(Whh1, Wp1);
  k_rec<<<64, 512, 0, stream>>>(G, Wp1, bhh1, tau1, out, 0, H1);

  // Layer 2: gi2 = [X | H1] @ W_ih2 + b_ih2; pack W_hh2; recurrence.
  k_gemm<<<dim3(6, 256), 256, 0, stream>>>(enc, H1, Wt2, bih2, G, 1024, 1024);
  k_prepw<<<24, 512, 0, stream>>>(Whh2, Wp2);
  k_rec<<<64, 512, 0, stream>>>(G, Wp2, bhh2, tau2, out, 256, (f16*)0);
}